// Round 1
// 192.053 us; speedup vs baseline: 1.0883x; 1.0883x over previous
//
#include <hip/hip_runtime.h>
#include <float.h>

#define DEVI __device__ __forceinline__

namespace {

constexpr int NB   = 8;     // batch
constexpr int CD   = 256;   // dense channels
constexpr int CS   = 512;   // sparse channels
constexpr int MM   = 4096;  // dense points
constexpr int SS   = 1024;  // sparse points
constexpr int NN   = 4096;  // pcd points
constexpr int KTOT = 768;   // CD + CS
constexpr int OC   = 256;   // output channels
constexpr float KEPS  = 1e-8f;
constexpr float BNEPS = 1e-5f;
constexpr float SLOPE = 0.2f;

// ---------------- workspace layout (bytes) — total ~10.6 MB ----------------
constexpr size_t OFF_Z    = 0;                              // float [NB][SS][OC]  Z = W_s * sparse
constexpr size_t SZ_Z     = (size_t)NB * SS * OC * 4;       // 8,388,608
constexpr size_t OFF_IDX3 = OFF_Z + SZ_Z;                   // int   [NB][MM][3]
constexpr size_t SZ_IDX3  = (size_t)NB * MM * 3 * 4;        // 393,216
constexpr size_t OFF_W3   = OFF_IDX3 + SZ_IDX3;             // float [NB][MM][3]
constexpr size_t OFF_WBF  = OFF_W3 + SZ_IDX3;               // bf16  [OC][KTOT]
constexpr size_t SZ_WBF   = (size_t)OC * KTOT * 2;          // 393,216
constexpr size_t OFF_PS   = OFF_WBF + SZ_WBF;               // float [512][OC] partial sums
constexpr size_t SZ_PS    = (size_t)512 * OC * 4;           // 524,288
constexpr size_t OFF_PS2  = OFF_PS + SZ_PS;                 // float [512][OC] partial sumsq
constexpr size_t OFF_MU   = OFF_PS2 + SZ_PS;                // float [OC]
constexpr size_t OFF_RS   = OFF_MU + 1024;                  // float [OC]

typedef __attribute__((ext_vector_type(8))) short s16x8;
typedef __attribute__((ext_vector_type(4))) float f32x4;

// float -> bf16 (RNE), returned as raw short
DEVI short f2bf(float f) {
  union { float f; unsigned u; } c; c.f = f;
  unsigned r = c.u + 0x7fffu + ((c.u >> 16) & 1u);
  return (short)(r >> 16);
}

// ---------------------------------------------------------------- conv_w -> bf16
__global__ void k_wcast(const float* __restrict__ w, short* __restrict__ wbf) {
  int i = blockIdx.x * 256 + threadIdx.x;   // grid covers OC*KTOT exactly
  wbf[i] = f2bf(w[i]);
}

// ---------------------------------------------------------------- KNN top-3
// (unchanged from verified baseline)
__global__ __launch_bounds__(256) void k_knn(
    const int* __restrict__ didx, const int* __restrict__ sidx,
    const float* __restrict__ pcd,
    int* __restrict__ idx3, float* __restrict__ w3,
    float* __restrict__ outIdxF) {
  __shared__ float4 sxyz[SS];              // 16 KB candidate coords
  __shared__ float  pd[4][64][3];          // partial top-3 dists
  __shared__ int    pi[4][64][3];          // partial top-3 idxs

  int blk = blockIdx.x;                    // 8 * 64 = 512 blocks
  int b   = blk >> 6;
  int m0  = (blk & 63) << 6;
  int tid = threadIdx.x;
  const float* pb = pcd + (size_t)b * 3 * NN;

  for (int s = tid; s < SS; s += 256) {
    int si = sidx[b * SS + s];
    sxyz[s] = make_float4(pb[si], pb[NN + si], pb[2 * NN + si], 0.f);
  }

  int p     = tid & 63;                    // point within tile
  int chunk = tid >> 6;                    // candidate chunk
  int m     = m0 + p;
  int di    = didx[b * MM + m];
  float px = pb[di], py = pb[NN + di], pz = pb[2 * NN + di];

  if (chunk == 0) outIdxF[b * MM + m] = (float)di;   // output 1

  __syncthreads();

  float d0 = FLT_MAX, d1 = FLT_MAX, d2 = FLT_MAX;
  int   i0 = 0, i1 = 0, i2 = 0;
  int s0c = chunk << 8;
#pragma unroll 4
  for (int t = 0; t < 256; ++t) {
    int s = s0c + t;
    float4 c = sxyz[s];
    float dx = c.x - px, dy = c.y - py, dz = c.z - pz;
    float d  = dx * dx + dy * dy + dz * dz;
    bool lt0 = d < d0, lt1 = d < d1, lt2 = d < d2;
    d2 = lt1 ? d1 : (lt2 ? d : d2);  i2 = lt1 ? i1 : (lt2 ? s : i2);
    d1 = lt0 ? d0 : (lt1 ? d : d1);  i1 = lt0 ? i0 : (lt1 ? s : i1);
    d0 = lt0 ? d  : d0;              i0 = lt0 ? s : i0;
  }
  pd[chunk][p][0] = d0; pd[chunk][p][1] = d1; pd[chunk][p][2] = d2;
  pi[chunk][p][0] = i0; pi[chunk][p][1] = i1; pi[chunk][p][2] = i2;
  __syncthreads();

  if (tid < 64) {
    float e0 = FLT_MAX, e1 = FLT_MAX, e2 = FLT_MAX;
    int   j0 = 0, j1 = 0, j2 = 0;
#pragma unroll
    for (int c = 0; c < 4; ++c)
#pragma unroll
      for (int r = 0; r < 3; ++r) {
        float d = pd[c][p][r]; int s = pi[c][p][r];
        bool lt0 = d < e0, lt1 = d < e1, lt2 = d < e2;
        e2 = lt1 ? e1 : (lt2 ? d : e2);  j2 = lt1 ? j1 : (lt2 ? s : j2);
        e1 = lt0 ? e0 : (lt1 ? d : e1);  j1 = lt0 ? j0 : (lt1 ? s : j1);
        e0 = lt0 ? d  : e0;              j0 = lt0 ? s : j0;
      }
    float w0 = 1.f / (e0 + KEPS), w1 = 1.f / (e1 + KEPS), w2 = 1.f / (e2 + KEPS);
    float inv = 1.f / (w0 + w1 + w2);
    int base = (b * MM + m) * 3;
    idx3[base] = j0; idx3[base + 1] = j1; idx3[base + 2] = j2;
    w3[base] = w0 * inv; w3[base + 1] = w1 * inv; w3[base + 2] = w2 * inv;
  }
}

// ---------------------------------------------------------------- Z = W_s * sparse
// Z[b][s][o] = sum_c W[o][CD+c] * sp[b][c][s].  Tile: 32 s x 256 o, BK=64.
// sp transposed inline via LDS (reads coalesced float4 along s).
__global__ __launch_bounds__(256) void k_gemmZ(
    const float* __restrict__ sp, const short* __restrict__ wbf,
    float* __restrict__ Z) {
  __shared__ __align__(16) short Wl[256 * 72];   // [o][k] pad 64->72 (144B rows)
  __shared__ __align__(16) short Sl[32 * 72];    // [s][k] pad 64->72

  int blk = blockIdx.x;                 // 8 * 32 = 256 blocks
  int st = blk & 31, b = blk >> 5;
  int s0 = st * 32;
  int tid = threadIdx.x, wv = tid >> 6, lane = tid & 63;
  int lo = lane & 15, quad = lane >> 4;

  f32x4 acc[4][2] = {};
  for (int k0 = 0; k0 < CS; k0 += 64) {
    __syncthreads();
    // stage W_s slice [256][64] bf16 via b128
#pragma unroll
    for (int r = 0; r < 8; ++r) {
      int lin = r * 256 + tid, row = lin >> 3, c8 = lin & 7;
      uint4 v = *(const uint4*)((const unsigned short*)wbf + (size_t)row * KTOT + CD + k0 + c8 * 8);
      *(uint4*)(&Wl[row * 72 + c8 * 8]) = v;
    }
    // stage sp slice [64 c][32 s] -> Sl[s][c] (inline transpose + f32->bf16)
#pragma unroll
    for (int r = 0; r < 2; ++r) {
      int lin = r * 256 + tid, cc = lin >> 3, s4 = lin & 7;
      float4 v = *(const float4*)(sp + (size_t)(b * CS + k0 + cc) * SS + s0 + s4 * 4);
      Sl[(s4 * 4 + 0) * 72 + cc] = f2bf(v.x);
      Sl[(s4 * 4 + 1) * 72 + cc] = f2bf(v.y);
      Sl[(s4 * 4 + 2) * 72 + cc] = f2bf(v.z);
      Sl[(s4 * 4 + 3) * 72 + cc] = f2bf(v.w);
    }
    __syncthreads();
    s16x8 af[2][4], bfr[2][2];
#pragma unroll
    for (int h = 0; h < 2; ++h) {
#pragma unroll
      for (int i = 0; i < 4; ++i)
        af[h][i] = *(const s16x8*)(&Wl[(wv * 64 + i * 16 + lo) * 72 + h * 32 + quad * 8]);
#pragma unroll
      for (int j = 0; j < 2; ++j)
        bfr[h][j] = *(const s16x8*)(&Sl[(j * 16 + lo) * 72 + h * 32 + quad * 8]);
    }
#pragma unroll
    for (int h = 0; h < 2; ++h)
#pragma unroll
      for (int i = 0; i < 4; ++i)
#pragma unroll
        for (int j = 0; j < 2; ++j)
          acc[i][j] = __builtin_amdgcn_mfma_f32_16x16x32_bf16(af[h][i], bfr[h][j], acc[i][j], 0, 0, 0);
  }
  // write Z[b][s][o] — lane's 4 regs are 4 consecutive o -> float4 store
#pragma unroll
  for (int i = 0; i < 4; ++i)
#pragma unroll
    for (int j = 0; j < 2; ++j) {
      int s = j * 16 + lo, o = wv * 64 + i * 16 + quad * 4;
      *(f32x4*)(Z + (size_t)(b * SS + s0 + s) * OC + o) = acc[i][j];
    }
}

// ---------------------------------------------------------------- dense GEMM + combine + stats
// y[b][o][m] = sum_k W[o][k]*dense_bf[b][k][m]  (k<256)
//            + sum_j w3[m][j] * Z[b][idx3[m][j]][o]
// Tile: 64 m x 256 o (full OC), 4 waves each 64o x 64m. K=256, BK=64 -> 4 steps.
// Epilogue: gather Z rows (coalesced, L2/L3-resident) into LDS P, add, store,
// and accumulate deterministic per-block BN partial sums.
__global__ __launch_bounds__(256) void k_gemmDC(
    const float* __restrict__ dense, const float* __restrict__ Z,
    const int* __restrict__ idx3, const float* __restrict__ w3,
    const short* __restrict__ wbf, float* __restrict__ y,
    float* __restrict__ ps, float* __restrict__ ps2) {
  __shared__ __align__(16) short Wl[256 * 72];   // [o][k] pad 64->72; reused as P[32][260] f32
  __shared__ __align__(16) short Xl[64 * 72];    // [m][k] pad 64->72
  __shared__ int   mi3[192];
  __shared__ float mw3[192];

  int blk = blockIdx.x;                 // 8 * 64 = 512 blocks
  int mt = blk & 63, b = blk >> 6, m0 = mt << 6;
  int tid = threadIdx.x, wv = tid >> 6, lane = tid & 63;
  int lo = lane & 15, quad = lane >> 4;

  {
    int base = (b * MM + m0) * 3;
    for (int i = tid; i < 192; i += 256) { mi3[i] = idx3[base + i]; mw3[i] = w3[base + i]; }
  }

  f32x4 acc[4][4] = {};
  for (int k0 = 0; k0 < CD; k0 += 64) {
    __syncthreads();
    // stage W_d slice [256][64] bf16
#pragma unroll
    for (int r = 0; r < 8; ++r) {
      int lin = r * 256 + tid, row = lin >> 3, c8 = lin & 7;
      uint4 v = *(const uint4*)((const unsigned short*)wbf + (size_t)row * KTOT + k0 + c8 * 8);
      *(uint4*)(&Wl[row * 72 + c8 * 8]) = v;
    }
    // stage dense slice [64 k][64 m] -> Xl[m][k] (inline transpose + f32->bf16)
#pragma unroll
    for (int r = 0; r < 4; ++r) {
      int lin = r * 256 + tid, kk = lin >> 4, m4 = lin & 15;
      float4 v = *(const float4*)(dense + (size_t)(b * CD + k0 + kk) * MM + m0 + m4 * 4);
      Xl[(m4 * 4 + 0) * 72 + kk] = f2bf(v.x);
      Xl[(m4 * 4 + 1) * 72 + kk] = f2bf(v.y);
      Xl[(m4 * 4 + 2) * 72 + kk] = f2bf(v.z);
      Xl[(m4 * 4 + 3) * 72 + kk] = f2bf(v.w);
    }
    __syncthreads();
    s16x8 af[2][4], bfr[2][4];
#pragma unroll
    for (int h = 0; h < 2; ++h) {
#pragma unroll
      for (int i = 0; i < 4; ++i)
        af[h][i] = *(const s16x8*)(&Wl[(wv * 64 + i * 16 + lo) * 72 + h * 32 + quad * 8]);
#pragma unroll
      for (int j = 0; j < 4; ++j)
        bfr[h][j] = *(const s16x8*)(&Xl[(j * 16 + lo) * 72 + h * 32 + quad * 8]);
    }
#pragma unroll
    for (int h = 0; h < 2; ++h)
#pragma unroll
      for (int i = 0; i < 4; ++i)
#pragma unroll
        for (int j = 0; j < 4; ++j)
          acc[i][j] = __builtin_amdgcn_mfma_f32_16x16x32_bf16(af[h][i], bfr[h][j], acc[i][j], 0, 0, 0);
  }

  // ---------------- epilogue: combine with interp-projection, store, stats
  float* P = (float*)Wl;                 // [32][260] f32, pad 256->260 (16B-aligned rows)
  const float* Zb = Z + (size_t)b * SS * OC;
  float ss[4][4] = {}, s2s[4][4] = {};
  __syncthreads();                       // Wl reads done, safe to reuse as P

#pragma unroll
  for (int h = 0; h < 2; ++h) {
    // build P[ml][o] = sum_j w_j * Z[idx_j][o] for m-half h (coalesced 1KB-row reads)
#pragma unroll 4
    for (int ml = 0; ml < 32; ++ml) {
      int mg = (h * 32 + ml) * 3;
      float p = mw3[mg + 0] * Zb[(size_t)mi3[mg + 0] * OC + tid]
              + mw3[mg + 1] * Zb[(size_t)mi3[mg + 1] * OC + tid]
              + mw3[mg + 2] * Zb[(size_t)mi3[mg + 2] * OC + tid];
      P[ml * 260 + tid] = p;
    }
    __syncthreads();
#pragma unroll
    for (int i = 0; i < 4; ++i)
#pragma unroll
      for (int jj = 0; jj < 2; ++jj) {
        int j = h * 2 + jj, ml = jj * 16 + lo;
        int o = wv * 64 + i * 16 + quad * 4;
        f32x4 p = *(const f32x4*)(&P[ml * 260 + o]);
        f32x4 v = acc[i][j] + p;
        float* dst = y + ((size_t)(b * OC + o)) * MM + m0 + j * 16 + lo;
#pragma unroll
        for (int r = 0; r < 4; ++r) {
          float vv = v[r];
          dst[(size_t)r * MM] = vv;
          ss[i][r] += vv; s2s[i][r] += vv * vv;
        }
      }
    __syncthreads();
  }

  // reduce stats across the 16 m-lanes of each quad (deterministic), write partials
#pragma unroll
  for (int i = 0; i < 4; ++i)
#pragma unroll
    for (int r = 0; r < 4; ++r) {
      float a = ss[i][r], q = s2s[i][r];
      for (int off = 1; off < 16; off <<= 1) { a += __shfl_xor(a, off); q += __shfl_xor(q, off); }
      ss[i][r] = a; s2s[i][r] = q;
    }
  if (lo == 0) {
#pragma unroll
    for (int i = 0; i < 4; ++i)
#pragma unroll
      for (int r = 0; r < 4; ++r) {
        int o = wv * 64 + i * 16 + quad * 4 + r;
        ps[blk * OC + o]  = ss[i][r];
        ps2[blk * OC + o] = s2s[i][r];
      }
  }
}

// ---------------------------------------------------------------- BN finalize
__global__ void k_finalize(const float* __restrict__ ps, const float* __restrict__ ps2,
                           float* __restrict__ mu, float* __restrict__ rs) {
  int o = threadIdx.x;
  float s = 0.f, s2 = 0.f;
#pragma unroll 8
  for (int k = 0; k < 512; ++k) { s += ps[k * OC + o]; s2 += ps2[k * OC + o]; }
  float mn = s / (float)(NB * MM);
  float vr = s2 / (float)(NB * MM) - mn * mn;
  mu[o] = mn;
  rs[o] = rsqrtf(vr + BNEPS);
}

// ---------------------------------------------------------------- BN apply + LeakyReLU
__global__ void k_norm(float* __restrict__ y, const float* __restrict__ mu,
                       const float* __restrict__ rs, const float* __restrict__ gamma,
                       const float* __restrict__ beta) {
  int i = blockIdx.x * 256 + threadIdx.x;   // float4 index; grid covers exactly
  int o = (i >> 10) & 255;                  // 1024 float4 per (b,o) row
  float mn = mu[o], a = rs[o] * gamma[o], be = beta[o];
  float4 v = ((const float4*)y)[i];
  float t;
  t = (v.x - mn) * a + be; v.x = t >= 0.f ? t : SLOPE * t;
  t = (v.y - mn) * a + be; v.y = t >= 0.f ? t : SLOPE * t;
  t = (v.z - mn) * a + be; v.z = t >= 0.f ? t : SLOPE * t;
  t = (v.w - mn) * a + be; v.w = t >= 0.f ? t : SLOPE * t;
  ((float4*)y)[i] = v;
}

}  // namespace

extern "C" void kernel_launch(void* const* d_in, const int* in_sizes, int n_in,
                              void* d_out, int out_size, void* d_ws, size_t ws_size,
                              hipStream_t stream) {
  const float* dense = (const float*)d_in[0];
  const int*   didx  = (const int*)d_in[1];
  const float* sp    = (const float*)d_in[2];
  const int*   sidx  = (const int*)d_in[3];
  const float* pcd   = (const float*)d_in[4];
  const float* convw = (const float*)d_in[5];
  const float* gamma = (const float*)d_in[6];
  const float* beta  = (const float*)d_in[7];

  float* y = (float*)d_out;                       // [8][256][4096] raw -> normalized in place
  float* outIdxF = y + (size_t)NB * OC * MM;      // output 1: dense_idx as float

  char* ws = (char*)d_ws;                         // needs ~10.6 MB
  float* Z    = (float*)(ws + OFF_Z);
  int*   idx3 = (int*)(ws + OFF_IDX3);
  float* w3   = (float*)(ws + OFF_W3);
  short* wbf  = (short*)(ws + OFF_WBF);
  float* ps   = (float*)(ws + OFF_PS);
  float* ps2  = (float*)(ws + OFF_PS2);
  float* mu   = (float*)(ws + OFF_MU);
  float* rs   = (float*)(ws + OFF_RS);

  k_wcast   <<<(OC * KTOT) / 256, 256, 0, stream>>>(convw, wbf);
  k_knn     <<<NB * (MM / 64), 256, 0, stream>>>(didx, sidx, pcd, idx3, w3, outIdxF);
  k_gemmZ   <<<NB * (SS / 32), 256, 0, stream>>>(sp, wbf, Z);
  k_gemmDC  <<<NB * (MM / 64), 256, 0, stream>>>(dense, Z, idx3, w3, wbf, y, ps, ps2);
  k_finalize<<<1, 256, 0, stream>>>(ps, ps2, mu, rs);
  k_norm    <<<(NB * OC * MM / 4) / 256, 256, 0, stream>>>(y, mu, rs, gamma, beta);
}